// Round 1
// baseline (424.257 us; speedup 1.0000x reference)
//
#include <hip/hip_runtime.h>
#include <math.h>

#define KF 8
#define LL 8
#define TT (1 << 18)
#define FF 2
#define HID 64
#define INF 16          // L*F = MLP input dim
// LDS strides (floats), chosen so the 8 per-lane 'assign' values map to
// distinct/2-way bank groups for float4 reads:
//   W1: stride 1056 -> (1056/4)%32 = 8 bank-group step per cluster
#define W1S 1056
#define BS  68          // b1 / W2 per-cluster stride (68%32=4 offset; 2-way max)

__global__ __launch_bounds__(256) void propnet_density_kernel(
    const float* __restrict__ positions,
    const float* __restrict__ centroids,
    const float* __restrict__ tables,
    const float* __restrict__ W1,
    const float* __restrict__ b1,
    const float* __restrict__ W2,
    const float* __restrict__ b2,
    float* __restrict__ out,
    int npts)
{
    __shared__ float sW1[KF * W1S];   // 33792 B
    __shared__ float sB1[KF * BS];    //  2176 B
    __shared__ float sW2[KF * BS];    //  2176 B
    __shared__ float sB2[KF];
    __shared__ float sC[KF * 3];

    const int tid = threadIdx.x;

    // ---- cooperative weight staging (coalesced global reads) ----
    for (int idx = tid; idx < KF * INF * HID; idx += blockDim.x) {
        int k = idx >> 10;            // / (16*64)
        int r = idx & 1023;
        sW1[k * W1S + r] = W1[idx];
    }
    for (int idx = tid; idx < KF * HID; idx += blockDim.x) {
        int k = idx >> 6;
        int r = idx & 63;
        sB1[k * BS + r] = b1[idx];
        sW2[k * BS + r] = W2[idx];
    }
    if (tid < KF) sB2[tid] = b2[tid];
    if (tid < KF * 3) sC[tid] = centroids[tid];
    __syncthreads();

    const int gid = blockIdx.x * blockDim.x + tid;
    if (gid >= npts) return;

    const float px = positions[gid * 3 + 0];
    const float py = positions[gid * 3 + 1];
    const float pz = positions[gid * 3 + 2];

    // ---- cluster assignment: argmin_k ||p - c_k||^2 (first-min tie-break) ----
    int assign = 0;
    float best = 1e30f;
    #pragma unroll
    for (int k = 0; k < KF; ++k) {
        float dx = px - sC[k * 3 + 0];
        float dy = py - sC[k * 3 + 1];
        float dz = pz - sC[k * 3 + 2];
        float d2 = fmaf(dx, dx, fmaf(dy, dy, dz * dz));
        bool lt = d2 < best;
        assign = lt ? k : assign;
        best = lt ? d2 : best;
    }

    // ---- multiresolution hash encoding ----
    float enc[INF];
    const float2* __restrict__ tab =
        (const float2*)tables + (size_t)assign * (LL * (size_t)TT);

    #pragma unroll
    for (int l = 0; l < LL; ++l) {
        const float res = (float)(16 << l);
        const float sx = px * res, sy = py * res, sz = pz * res;
        const float fx = floorf(sx), fy = floorf(sy), fz = floorf(sz);
        const float wx = sx - fx, wy = sy - fy, wz = sz - fz;
        const unsigned ix = (unsigned)(int)fx;
        const unsigned iy = (unsigned)(int)fy;
        const unsigned iz = (unsigned)(int)fz;

        const float2* __restrict__ tl = tab + (size_t)l * TT;

        const unsigned hx0 = ix;                         // prime 1
        const unsigned hx1 = ix + 1u;
        const unsigned hy0 = iy * 2654435761u;
        const unsigned hy1 = (iy + 1u) * 2654435761u;
        const unsigned hz0 = iz * 805459861u;
        const unsigned hz1 = (iz + 1u) * 805459861u;
        const unsigned M = TT - 1;

        // 8 independent 8B gathers — keep them all in flight
        const float2 c000 = tl[(hx0 ^ hy0 ^ hz0) & M];
        const float2 c001 = tl[(hx0 ^ hy0 ^ hz1) & M];
        const float2 c010 = tl[(hx0 ^ hy1 ^ hz0) & M];
        const float2 c011 = tl[(hx0 ^ hy1 ^ hz1) & M];
        const float2 c100 = tl[(hx1 ^ hy0 ^ hz0) & M];
        const float2 c101 = tl[(hx1 ^ hy0 ^ hz1) & M];
        const float2 c110 = tl[(hx1 ^ hy1 ^ hz0) & M];
        const float2 c111 = tl[(hx1 ^ hy1 ^ hz1) & M];

        const float ux = 1.f - wx, uy = 1.f - wy, uz = 1.f - wz;
        const float w000 = ux * uy * uz, w001 = ux * uy * wz;
        const float w010 = ux * wy * uz, w011 = ux * wy * wz;
        const float w100 = wx * uy * uz, w101 = wx * uy * wz;
        const float w110 = wx * wy * uz, w111 = wx * wy * wz;

        enc[l * 2 + 0] = c000.x * w000 + c001.x * w001 + c010.x * w010 + c011.x * w011
                       + c100.x * w100 + c101.x * w101 + c110.x * w110 + c111.x * w111;
        enc[l * 2 + 1] = c000.y * w000 + c001.y * w001 + c010.y * w010 + c011.y * w011
                       + c100.y * w100 + c101.y * w101 + c110.y * w110 + c111.y * w111;
    }

    // ---- per-cluster MLP: out = b2 + sum_j relu(b1[j] + enc·W1[:,j]) * W2[j] ----
    const float4* __restrict__ w1k = (const float4*)(sW1 + assign * W1S);
    const float4* __restrict__ b1k = (const float4*)(sB1 + assign * BS);
    const float4* __restrict__ w2k = (const float4*)(sW2 + assign * BS);

    float outv = sB2[assign];
    #pragma unroll
    for (int j4 = 0; j4 < HID / 4; ++j4) {
        float4 a = b1k[j4];
        #pragma unroll
        for (int i = 0; i < INF; ++i) {
            const float4 w = w1k[i * (HID / 4) + j4];   // ds_read_b128
            const float e = enc[i];
            a.x = fmaf(e, w.x, a.x);
            a.y = fmaf(e, w.y, a.y);
            a.z = fmaf(e, w.z, a.z);
            a.w = fmaf(e, w.w, a.w);
        }
        a.x = fmaxf(a.x, 0.f); a.y = fmaxf(a.y, 0.f);
        a.z = fmaxf(a.z, 0.f); a.w = fmaxf(a.w, 0.f);
        const float4 w2v = w2k[j4];
        outv = fmaf(a.x, w2v.x, outv);
        outv = fmaf(a.y, w2v.y, outv);
        outv = fmaf(a.z, w2v.z, outv);
        outv = fmaf(a.w, w2v.w, outv);
    }

    out[gid] = expf(outv);
}

extern "C" void kernel_launch(void* const* d_in, const int* in_sizes, int n_in,
                              void* d_out, int out_size, void* d_ws, size_t ws_size,
                              hipStream_t stream) {
    const float* positions = (const float*)d_in[0];
    const float* centroids = (const float*)d_in[1];
    const float* tables    = (const float*)d_in[2];
    const float* W1        = (const float*)d_in[3];
    const float* b1        = (const float*)d_in[4];
    const float* W2        = (const float*)d_in[5];
    const float* b2        = (const float*)d_in[6];
    float* out = (float*)d_out;

    const int npts = in_sizes[0] / 3;
    const int block = 256;
    const int grid = (npts + block - 1) / block;

    propnet_density_kernel<<<grid, block, 0, stream>>>(
        positions, centroids, tables, W1, b1, W2, b2, out, npts);
}